// Round 3
// baseline (240.597 us; speedup 1.0000x reference)
//
#include <hip/hip_runtime.h>

// MGN_NET: 3x NNConv(mean) + ReLU, then pairwise-L1 CBT [35x35]. All fp32.
// 2 dispatches: init (zero barrier counters) + mega-kernel (238 blocks x 512)
// with 4 software grid barriers. NO global atomics anywhere; all cross-block
// data moves through write-once message buffers with agent-scope (sc1/LLC)
// relaxed atomic ld/st, 8B-vectorized. Barrier = 8 spread counters (sum-poll).
// Phases:
//   PA (140 blk = 35n x 4og): edge-list scan -> elist/cnt; x1 slice -> ws
//   PB (238 blk = 119eg x 2ih): layer-2 edge msgs (i-half) -> mp[2][E][256]
//   PC (140 blk = 35n x 4og): x2 = relu(gather(mp)/c + lin2.x1 + b2)
//   PD (238 blk x 5e): layer-3 edge msgs -> mp3[E][64]
//   PE (35 blk): x3 all-nodes recompute (gather mp3 + lin3.x2) + CBT -> out
// 238 blocks <= 256 CUs => grid co-resident => barrier deadlock-free.

#define NN 35
#define NE 1190
#define NBLK 238
#define TE2 10
#define TE3 5
#define MAXE 96

// float offsets into ws (bar occupies [0,16) as u32)
#define OFF_CNT 64       // 35
#define OFF_EL  128      // ints, 35*96 = 3360 -> ends 3488
#define OFF_X1  3584     // 8960 -> 12544
#define OFF_X2  12544    // 8960 -> 21504
#define OFF_MP  21504    // 2*1190*256 = 609280 -> 630784
#define OFF_MP3 630784   // 1190*64 = 76160 -> 706944

__global__ __launch_bounds__(64) void init_k(unsigned* bar) {
    if (threadIdx.x < 16) bar[threadIdx.x] = 0u;
}

// Agent-scope (LLC-coherent, sc1) relaxed accessors. 8B where possible.
__device__ __forceinline__ float ld_c(const float* p) {
    return __hip_atomic_load(p, __ATOMIC_RELAXED, __HIP_MEMORY_SCOPE_AGENT);
}
__device__ __forceinline__ void st_c(float* p, float v) {
    __hip_atomic_store(p, v, __ATOMIC_RELAXED, __HIP_MEMORY_SCOPE_AGENT);
}
__device__ __forceinline__ int ld_ci(const int* p) {
    return __hip_atomic_load(p, __ATOMIC_RELAXED, __HIP_MEMORY_SCOPE_AGENT);
}
__device__ __forceinline__ void st_ci(int* p, int v) {
    __hip_atomic_store(p, v, __ATOMIC_RELAXED, __HIP_MEMORY_SCOPE_AGENT);
}
__device__ __forceinline__ float2 ld_c2(const float* p) {
    union { double d; float2 f; } u;
    u.d = __hip_atomic_load((const double*)p, __ATOMIC_RELAXED,
                            __HIP_MEMORY_SCOPE_AGENT);
    return u.f;
}
__device__ __forceinline__ void st_c2(float* p, float2 v) {
    union { double d; float2 f; } u;
    u.f = v;
    __hip_atomic_store((double*)p, u.d, __ATOMIC_RELAXED,
                       __HIP_MEMORY_SCOPE_AGENT);
}

// Grid barrier, 8 spread counters to avoid single-address RMW serialization.
// Sum-poll is correct: by induction, sum >= NBLK*k implies every block has
// arrived k times (a block can only arrive k+1 times after observing
// sum >= NBLK*k, and at the first moment sum reaches NBLK*k no block has).
// Visibility: compiler emits s_waitcnt vmcnt(0) before s_barrier, so all
// sc1 stores are at the LLC before the arrive-add (also an LLC op).
__device__ __forceinline__ void gbar(unsigned* bar, unsigned target) {
    __syncthreads();
    if (threadIdx.x == 0) {
        __hip_atomic_fetch_add(bar + (blockIdx.x & 7), 1u, __ATOMIC_RELAXED,
                               __HIP_MEMORY_SCOPE_AGENT);
        for (;;) {
            unsigned s = 0;
#pragma unroll
            for (int i = 0; i < 8; i++)
                s += __hip_atomic_load(bar + i, __ATOMIC_RELAXED,
                                       __HIP_MEMORY_SCOPE_AGENT);
            if (s >= target) break;
            __builtin_amdgcn_s_sleep(2);
        }
        asm volatile("" ::: "memory");  // keep later loads below the spin
    }
    __syncthreads();
}

__global__ __launch_bounds__(512) void mega_k(
    float* __restrict__ ws, const float* __restrict__ x,
    const float* __restrict__ ea, const int* __restrict__ ei,
    const float* __restrict__ w1, const float* __restrict__ b1w,
    const float* __restrict__ lin1, const float* __restrict__ b1,
    const float* __restrict__ w2, const float* __restrict__ b2w,
    const float* __restrict__ lin2, const float* __restrict__ b2,
    const float* __restrict__ w3, const float* __restrict__ b3w,
    const float* __restrict__ lin3, const float* __restrict__ b3,
    float* __restrict__ out) {
    __shared__ float smem[16384];  // 64 KiB, re-purposed per phase
    unsigned* bar = (unsigned*)ws;
    const int tid = threadIdx.x;
    const int bid = blockIdx.x;

    // ---------------- PA: edge lists + x1 slices (140 blocks) --------------
    if (bid < 140) {
        const int n = bid >> 2, och = bid & 3;
        int* elistS = (int*)smem;            // 96
        int* ecntS = (int*)smem + 96;        // 1
        float* partS = smem + 128;           // 8*64
        if (tid == 0) *ecntS = 0;
        __syncthreads();
        for (int e = tid; e < NE; e += 512) {
            if (ei[NE + e] == n) {
                const int p = atomicAdd(ecntS, 1);
                if (p < MAXE) elistS[p] = e;
            }
        }
        __syncthreads();
        const int deg = *ecntS;
        const int dl = deg < MAXE ? deg : MAXE;
        const int ol = tid & 63, ech = tid >> 6;
        const int o = och * 64 + ol;
        const float2* wr = (const float2*)(w1 + o * 6);
        const float2 wv0 = wr[0], wv1 = wr[1], wv2 = wr[2];
        const float bb = b1w[o];
        float a = 0.f;
        for (int k = ech; k < dl; k += 8) {
            const int e = elistS[k];
            const float2* eap = (const float2*)(ea + e * 6);
            const float2 a0 = eap[0], a1 = eap[1], a2 = eap[2];
            float d = bb;
            d = fmaf(a0.x, wv0.x, d); d = fmaf(a0.y, wv0.y, d);
            d = fmaf(a1.x, wv1.x, d); d = fmaf(a1.y, wv1.y, d);
            d = fmaf(a2.x, wv2.x, d); d = fmaf(a2.y, wv2.y, d);
            a = fmaf(x[ei[e]], fmaxf(d, 0.f), a);
        }
        partS[ech * 64 + ol] = a;
        __syncthreads();
        if (ech == 0) {
            float s = a;
#pragma unroll
            for (int p = 1; p < 8; p++) s += partS[p * 64 + ol];
            const float c = fmaxf((float)deg, 1.f);
            st_c(ws + OFF_X1 + n * 256 + o,
                 fmaxf(s / c + x[n] * lin1[o] + b1[o], 0.f));
        }
        if (och == 0) {
            if (tid < dl) st_ci((int*)(ws + OFF_EL) + n * MAXE + tid, elistS[tid]);
            if (tid == 0) st_c(ws + OFF_CNT + n, (float)deg);
        }
    }
    gbar(bar, NBLK * 1u);

    // ---------------- PB: layer-2 edge messages -> mp ----------------------
    {
        const int eg = bid >> 1, ig = bid & 1;
        const int e0 = eg * TE2;
        int* srcsS = (int*)smem;         // 10
        float* easS = smem + 16;         // 60
        float* xsS = smem + 96;          // 10*128 -> ends 1376
        float* partS = smem + 1408;      // 10*256 -> ends 3968
        if (tid < TE2) srcsS[tid] = ei[e0 + tid];
        if (tid >= 64 && tid < 64 + TE2 * 6) {
            const int t = tid - 64;
            easS[t] = ea[e0 * 6 + t];
        }
        __syncthreads();
        for (int idx = tid; idx < TE2 * 64; idx += 512) {
            const int te = idx >> 6, ip = (idx & 63) * 2;
            *(float2*)&xsS[te * 128 + ip] =
                ld_c2(ws + OFF_X1 + srcsS[te] * 256 + ig * 128 + ip);
        }
        __syncthreads();
        const int o = tid & 255, ich = tid >> 8;
        float ear[TE2][6];
#pragma unroll
        for (int te = 0; te < TE2; te++)
#pragma unroll
            for (int v = 0; v < 6; v++) ear[te][v] = easS[te * 6 + v];
        float acc[TE2] = {};
        for (int ii = 0; ii < 64; ii++) {
            const int il = ich * 64 + ii;
            const int i = ig * 128 + il;
            const float* wp = w2 + (size_t)(i * 256 + o) * 6;
            const float2 wa = *(const float2*)wp;
            const float2 wb = *(const float2*)(wp + 2);
            const float2 wc = *(const float2*)(wp + 4);
            const float b = b2w[i * 256 + o];
#pragma unroll
            for (int te = 0; te < TE2; te += 2) {
                float dx = b, dy = b;
                dx = fmaf(ear[te][0], wa.x, dx); dy = fmaf(ear[te+1][0], wa.x, dy);
                dx = fmaf(ear[te][1], wa.y, dx); dy = fmaf(ear[te+1][1], wa.y, dy);
                dx = fmaf(ear[te][2], wb.x, dx); dy = fmaf(ear[te+1][2], wb.x, dy);
                dx = fmaf(ear[te][3], wb.y, dx); dy = fmaf(ear[te+1][3], wb.y, dy);
                dx = fmaf(ear[te][4], wc.x, dx); dy = fmaf(ear[te+1][4], wc.x, dy);
                dx = fmaf(ear[te][5], wc.y, dx); dy = fmaf(ear[te+1][5], wc.y, dy);
                dx = fmaxf(dx, 0.f);             dy = fmaxf(dy, 0.f);
                acc[te]   = fmaf(xsS[te * 128 + il], dx, acc[te]);
                acc[te+1] = fmaf(xsS[(te+1) * 128 + il], dy, acc[te+1]);
            }
        }
        if (ich == 1) {
#pragma unroll
            for (int te = 0; te < TE2; te++) partS[te * 256 + o] = acc[te];
        }
        __syncthreads();
        if (ich == 0) {
#pragma unroll
            for (int te = 0; te < TE2; te++) partS[te * 256 + o] += acc[te];
        }
        __syncthreads();
        for (int idx = tid; idx < TE2 * 128; idx += 512) {
            const int te = idx >> 7, op = (idx & 127) * 2;
            st_c2(ws + OFF_MP + ((size_t)ig * NE + e0 + te) * 256 + op,
                  *(float2*)&partS[te * 256 + op]);
        }
    }
    gbar(bar, NBLK * 2u);

    // ---------------- PC: x2 = relu(gather(mp)/c + lin2.x1 + b2) -----------
    if (bid < 140) {
        const int n = bid >> 2, og = bid & 3;
        float* x1S = smem;               // 256
        float* pg = smem + 256;          // 8*64
        float* pm = smem + 768;          // 8*64
        float* cS = smem + 1280;         // 1
        int* elS = (int*)(smem + 1344);  // 96
        if (tid == 0) cS[0] = ld_c(ws + OFF_CNT + n);
        if (tid < MAXE) elS[tid] = ld_ci((const int*)(ws + OFF_EL) + n * MAXE + tid);
        if (tid >= 128 && tid < 256) {
            const int ip = (tid - 128) * 2;
            *(float2*)&x1S[ip] = ld_c2(ws + OFF_X1 + n * 256 + ip);
        }
        __syncthreads();
        const int deg = (int)cS[0];
        const int ol = tid & 63, kc = tid >> 6;
        const int o = og * 64 + ol;
        float g = 0.f;
        for (int k = kc; k < deg; k += 8) {
            const int e = elS[k];
            g += ld_c(ws + OFF_MP + (size_t)e * 256 + o)
               + ld_c(ws + OFF_MP + (size_t)(NE + e) * 256 + o);
        }
        float s = 0.f;
        const float4* l4 = (const float4*)(lin2 + (size_t)o * 256 + kc * 32);
        const float* xs = x1S + kc * 32;
#pragma unroll
        for (int k = 0; k < 8; k++) {
            const float4 wv = l4[k];
            s = fmaf(wv.x, xs[k * 4], s);
            s = fmaf(wv.y, xs[k * 4 + 1], s);
            s = fmaf(wv.z, xs[k * 4 + 2], s);
            s = fmaf(wv.w, xs[k * 4 + 3], s);
        }
        pg[kc * 64 + ol] = g;
        pm[kc * 64 + ol] = s;
        __syncthreads();
        if (kc == 0) {
#pragma unroll
            for (int p = 1; p < 8; p++) {
                g += pg[p * 64 + ol];
                s += pm[p * 64 + ol];
            }
            const float c = fmaxf(cS[0], 1.f);
            st_c(ws + OFF_X2 + n * 256 + o, fmaxf(g / c + s + b2[o], 0.f));
        }
    }
    gbar(bar, NBLK * 3u);

    // ---------------- PD: layer-3 edge messages -> mp3 ---------------------
    {
        const int e0 = bid * TE3;
        int* srcsS = (int*)smem;         // 8
        float* easS = smem + 8;          // 30
        float* xsS = smem + 64;          // 5*256 -> ends 1344
        float* partS = smem + 1344;      // 7*5*64 -> ends 3584
        float* finS = smem + 3584;       // 320
        if (tid < TE3) srcsS[tid] = ei[e0 + tid];
        if (tid >= 64 && tid < 64 + TE3 * 6) {
            const int t = tid - 64;
            easS[t] = ea[e0 * 6 + t];
        }
        __syncthreads();
        for (int idx = tid; idx < TE3 * 128; idx += 512) {
            const int te = idx >> 7, ip = (idx & 127) * 2;
            *(float2*)&xsS[te * 256 + ip] =
                ld_c2(ws + OFF_X2 + srcsS[te] * 256 + ip);
        }
        __syncthreads();
        const int o3 = tid & 63, ic = tid >> 6;
        float ear[TE3][6];
#pragma unroll
        for (int te = 0; te < TE3; te++)
#pragma unroll
            for (int v = 0; v < 6; v++) ear[te][v] = easS[te * 6 + v];
        float acc[TE3] = {};
        for (int ii = 0; ii < 32; ii++) {
            const int i = ic * 32 + ii;
            const float* wp = w3 + (size_t)(i * 64 + o3) * 6;
            const float2 wa = *(const float2*)wp;
            const float2 wb = *(const float2*)(wp + 2);
            const float2 wc = *(const float2*)(wp + 4);
            const float b = b3w[i * 64 + o3];
#pragma unroll
            for (int te = 0; te < TE3; te++) {
                float d = b;
                d = fmaf(ear[te][0], wa.x, d);
                d = fmaf(ear[te][1], wa.y, d);
                d = fmaf(ear[te][2], wb.x, d);
                d = fmaf(ear[te][3], wb.y, d);
                d = fmaf(ear[te][4], wc.x, d);
                d = fmaf(ear[te][5], wc.y, d);
                acc[te] = fmaf(xsS[te * 256 + i], fmaxf(d, 0.f), acc[te]);
            }
        }
        if (ic > 0) {
#pragma unroll
            for (int te = 0; te < TE3; te++)
                partS[(ic - 1) * 320 + te * 64 + o3] = acc[te];
        }
        __syncthreads();
        if (ic == 0) {
#pragma unroll
            for (int te = 0; te < TE3; te++) {
                float s = acc[te];
#pragma unroll
                for (int p = 0; p < 7; p++) s += partS[p * 320 + te * 64 + o3];
                finS[te * 64 + o3] = s;
            }
        }
        __syncthreads();
        if (tid < 160) {
            const int te = tid >> 5, op = (tid & 31) * 2;
            st_c2(ws + OFF_MP3 + (size_t)(e0 + te) * 64 + op,
                  *(float2*)&finS[te * 64 + op]);
        }
    }
    gbar(bar, NBLK * 4u);

    // ---------------- PE: x3 recompute (all nodes) + CBT -------------------
    if (bid < NN) {
        float* x2S = smem;                 // 8960
        float* x3S = smem + 8960;          // 2240
        float* cntS = smem + 11200;        // 35 (+pad)
        int* elS = (int*)(smem + 11264);   // 3360 ints
        if (tid < NN) cntS[tid] = ld_c(ws + OFF_CNT + tid);
        for (int idx = tid; idx < NN * MAXE; idx += 512)
            elS[idx] = ld_ci((const int*)(ws + OFF_EL) + idx);
        for (int idx = tid; idx < 4480; idx += 512)
            *(float2*)&x2S[idx * 2] = ld_c2(ws + OFF_X2 + idx * 2);
        __syncthreads();
        const int f2 = (tid & 31) * 2, jg = tid >> 5;  // 16 j-groups
        const float4* r0 = (const float4*)(lin3 + f2 * 256);
        const float4* r1 = (const float4*)(lin3 + (f2 + 1) * 256);
        const float b30 = b3[f2], b31 = b3[f2 + 1];
        for (int j = jg; j < NN; j += 16) {
            const int deg = (int)cntS[j];
            const int* el = elS + j * MAXE;
            float g0 = 0.f, g1 = 0.f;
            for (int k = 0; k < deg; k++) {
                const float2 m = ld_c2(ws + OFF_MP3 + (size_t)el[k] * 64 + f2);
                g0 += m.x;
                g1 += m.y;
            }
            float s0 = 0.f, s1 = 0.f;
            const float4* xv = (const float4*)&x2S[j * 256];
#pragma unroll 16
            for (int icq = 0; icq < 64; icq++) {
                const float4 a = r0[icq], b = r1[icq], v = xv[icq];
                s0 = fmaf(a.x, v.x, s0); s1 = fmaf(b.x, v.x, s1);
                s0 = fmaf(a.y, v.y, s0); s1 = fmaf(b.y, v.y, s1);
                s0 = fmaf(a.z, v.z, s0); s1 = fmaf(b.z, v.z, s1);
                s0 = fmaf(a.w, v.w, s0); s1 = fmaf(b.w, v.w, s1);
            }
            const float c = fmaxf(cntS[j], 1.f);
            x3S[j * 64 + f2]     = fmaxf(g0 / c + s0 + b30, 0.f);
            x3S[j * 64 + f2 + 1] = fmaxf(g1 / c + s1 + b31, 0.f);
        }
        __syncthreads();
        const int f = tid & 63, jg2 = tid >> 6;
        const float xi = x3S[bid * 64 + f];
        for (int j = jg2; j < NN; j += 8) {
            float d = fabsf(xi - x3S[j * 64 + f]);
#pragma unroll
            for (int off = 32; off > 0; off >>= 1) d += __shfl_xor(d, off);
            if (f == 0) out[bid * NN + j] = d;
        }
    }
}

extern "C" void kernel_launch(void* const* d_in, const int* in_sizes, int n_in,
                              void* d_out, int out_size, void* d_ws, size_t ws_size,
                              hipStream_t stream) {
    (void)in_sizes; (void)n_in; (void)out_size; (void)ws_size;
    const float* x    = (const float*)d_in[0];
    const float* ea   = (const float*)d_in[1];
    const int*   ei   = (const int*)d_in[2];
    const float* nn1w = (const float*)d_in[3];
    const float* nn1b = (const float*)d_in[4];
    const float* lin1 = (const float*)d_in[5];
    const float* b1   = (const float*)d_in[6];
    const float* nn2w = (const float*)d_in[7];
    const float* nn2b = (const float*)d_in[8];
    const float* lin2 = (const float*)d_in[9];
    const float* b2   = (const float*)d_in[10];
    const float* nn3w = (const float*)d_in[11];
    const float* nn3b = (const float*)d_in[12];
    const float* lin3 = (const float*)d_in[13];
    const float* b3   = (const float*)d_in[14];

    float* ws = (float*)d_ws;
    init_k<<<1, 64, 0, stream>>>((unsigned*)d_ws);
    mega_k<<<NBLK, 512, 0, stream>>>(ws, x, ea, ei, nn1w, nn1b, lin1, b1,
                                     nn2w, nn2b, lin2, b2, nn3w, nn3b,
                                     lin3, b3, (float*)d_out);
}

// Round 4
// 155.727 us; speedup vs baseline: 1.5450x; 1.5450x over previous
//
#include <hip/hip_runtime.h>

// MGN_NET: 3x NNConv(mean) + ReLU, then pairwise-L1 CBT [35x35]. All fp32.
// 2 dispatches: init (zero barrier counters) + mega-kernel (238 blocks x 512)
// with 4 software grid barriers + one 35-way flag.
// Structure = round-2 (measured 90 us) + targeted fixes:
//  * barrier arrivals spread over 8 DISTINCT cache lines (bar[i*16])
//  * agg2/agg3 4-way replicated (bid&3) -> atomic same-line contention /4
//  * x3+CBT fused behind a cheap 35-arrival flag (one fewer full barrier)
//  * deg persisted in PA; no edge rescans in later phases
// Coherence: cross-block data via agent-scope relaxed atomics (sc1 -> LLC);
// aggregation via device atomicAdd (LLC-coherent). Barriers are fence-free:
// __syncthreads() drains vmcnt, so sc1 stores are at LLC before arrival.
// 238 blocks <= 256 CUs => grid co-resident => barrier deadlock-free.

#define NN 35
#define NE 1190
#define NBLK 238
#define TE2 10
#define TE3 5
#define MAXE 96

// float offsets into ws (u32 bar region [0,160))
#define OFF_CNT  160     // 35
#define OFF_X1   256     // 8960 -> 9216
#define OFF_X2   9216    // 8960 -> 18176
#define OFF_X3   18176   // 2240 -> 20416
#define OFF_AGG2 20480   // 4*8960 = 35840 -> 56320
#define OFF_AGG3 56320   // 4*2240 = 8960  -> 65280  (contiguous with AGG2)
#define NZERO2   22400   // (35840+8960)/2 float2 zero-stores

__global__ __launch_bounds__(64) void init_k(unsigned* bar) {
    for (int i = threadIdx.x; i < 160; i += 64) bar[i] = 0u;
}

// Agent-scope (LLC-coherent, sc1) relaxed accessors.
__device__ __forceinline__ float ld_c(const float* p) {
    return __hip_atomic_load(p, __ATOMIC_RELAXED, __HIP_MEMORY_SCOPE_AGENT);
}
__device__ __forceinline__ void st_c(float* p, float v) {
    __hip_atomic_store(p, v, __ATOMIC_RELAXED, __HIP_MEMORY_SCOPE_AGENT);
}
__device__ __forceinline__ float2 ld_c2(const float* p) {
    union { double d; float2 f; } u;
    u.d = __hip_atomic_load((const double*)p, __ATOMIC_RELAXED,
                            __HIP_MEMORY_SCOPE_AGENT);
    return u.f;
}
__device__ __forceinline__ void st_c2(float* p, float2 v) {
    union { double d; float2 f; } u;
    u.f = v;
    __hip_atomic_store((double*)p, u.d, __ATOMIC_RELAXED,
                       __HIP_MEMORY_SCOPE_AGENT);
}

// Grid barrier: 8 counters on 8 DISTINCT 64B lines (bar[i*16]).
// Sum-poll correctness by induction on rounds; arrival adds spread across
// lines so the 238 RMWs parallelize ~8x. s_sleep(8) keeps poll pressure low.
__device__ __forceinline__ void gbar(unsigned* bar, unsigned target) {
    __syncthreads();
    if (threadIdx.x == 0) {
        __hip_atomic_fetch_add(bar + (blockIdx.x & 7) * 16, 1u,
                               __ATOMIC_RELAXED, __HIP_MEMORY_SCOPE_AGENT);
        for (;;) {
            unsigned s = 0;
#pragma unroll
            for (int i = 0; i < 8; i++)
                s += __hip_atomic_load(bar + i * 16, __ATOMIC_RELAXED,
                                       __HIP_MEMORY_SCOPE_AGENT);
            if (s >= target) break;
            __builtin_amdgcn_s_sleep(8);
        }
        asm volatile("" ::: "memory");
    }
    __syncthreads();
}

__global__ __launch_bounds__(512) void mega_k(
    float* __restrict__ ws, const float* __restrict__ x,
    const float* __restrict__ ea, const int* __restrict__ ei,
    const float* __restrict__ w1, const float* __restrict__ b1w,
    const float* __restrict__ lin1, const float* __restrict__ b1,
    const float* __restrict__ w2, const float* __restrict__ b2w,
    const float* __restrict__ lin2, const float* __restrict__ b2,
    const float* __restrict__ w3, const float* __restrict__ b3w,
    const float* __restrict__ lin3, const float* __restrict__ b3,
    float* __restrict__ out) {
    __shared__ float smem[4096];  // 16 KiB, re-purposed per phase
    unsigned* bar = (unsigned*)ws;
    const int tid = threadIdx.x;
    const int bid = blockIdx.x;

    // ---------------- PA: x1 slices (140 blk) + zero agg replicas ----------
    if (bid < 140) {
        const int n = bid >> 2, och = bid & 3;
        int* elistS = (int*)smem;            // 96
        int* ecntS = (int*)smem + 96;        // 1
        float* partS = smem + 128;           // 8*64
        if (tid == 0) *ecntS = 0;
        __syncthreads();
        for (int e = tid; e < NE; e += 512) {
            if (ei[NE + e] == n) {
                const int p = atomicAdd(ecntS, 1);
                if (p < MAXE) elistS[p] = e;
            }
        }
        __syncthreads();
        const int deg = *ecntS;
        const int dl = deg < MAXE ? deg : MAXE;
        const int ol = tid & 63, ech = tid >> 6;
        const int o = och * 64 + ol;
        const float2* wr = (const float2*)(w1 + o * 6);
        const float2 wv0 = wr[0], wv1 = wr[1], wv2 = wr[2];
        const float bb = b1w[o];
        float a = 0.f;
        for (int k = ech; k < dl; k += 8) {
            const int e = elistS[k];
            const float2* eap = (const float2*)(ea + e * 6);
            const float2 a0 = eap[0], a1 = eap[1], a2 = eap[2];
            float d = bb;
            d = fmaf(a0.x, wv0.x, d); d = fmaf(a0.y, wv0.y, d);
            d = fmaf(a1.x, wv1.x, d); d = fmaf(a1.y, wv1.y, d);
            d = fmaf(a2.x, wv2.x, d); d = fmaf(a2.y, wv2.y, d);
            a = fmaf(x[ei[e]], fmaxf(d, 0.f), a);
        }
        partS[ech * 64 + ol] = a;
        __syncthreads();
        if (ech == 0) {
            float s = a;
#pragma unroll
            for (int p = 1; p < 8; p++) s += partS[p * 64 + ol];
            const float c = fmaxf((float)deg, 1.f);
            st_c(ws + OFF_X1 + n * 256 + o,
                 fmaxf(s / c + x[n] * lin1[o] + b1[o], 0.f));
        }
        if (och == 0 && tid == 0) st_c(ws + OFF_CNT + n, (float)deg);
    } else {
        // zero 4x agg2 + 4x agg3 replicas (contiguous 44800 floats)
        const int idx = (bid - 140) * 512 + tid;
        if (idx < NZERO2) {
            float2 z; z.x = 0.f; z.y = 0.f;
            st_c2(ws + OFF_AGG2 + idx * 2, z);
        }
    }
    gbar(bar, NBLK * 1u);

    // ---------------- PB: layer-2 edge messages -> agg2 replica ------------
    {
        const int eg = bid >> 1, ig = bid & 1;
        const int e0 = eg * TE2;
        const int rep = bid & 3;
        int* srcsS = (int*)smem;         // 10
        int* dstsS = (int*)smem + 16;    // 10
        float* easS = smem + 32;         // 60
        float* xsS = smem + 96;          // 10*128 -> ends 1376
        float* partS = smem + 1408;      // 10*256 -> ends 3968
        if (tid < TE2) { srcsS[tid] = ei[e0 + tid]; dstsS[tid] = ei[NE + e0 + tid]; }
        if (tid >= 64 && tid < 64 + TE2 * 6) {
            const int t = tid - 64;
            easS[t] = ea[e0 * 6 + t];
        }
        __syncthreads();
        for (int idx = tid; idx < TE2 * 64; idx += 512) {
            const int te = idx >> 6, ip = (idx & 63) * 2;
            *(float2*)&xsS[te * 128 + ip] =
                ld_c2(ws + OFF_X1 + srcsS[te] * 256 + ig * 128 + ip);
        }
        __syncthreads();
        const int o = tid & 255, ich = tid >> 8;
        float ear[TE2][6];
#pragma unroll
        for (int te = 0; te < TE2; te++)
#pragma unroll
            for (int v = 0; v < 6; v++) ear[te][v] = easS[te * 6 + v];
        float acc[TE2] = {};
        for (int ii = 0; ii < 64; ii++) {
            const int il = ich * 64 + ii;
            const int i = ig * 128 + il;
            const float* wp = w2 + (size_t)(i * 256 + o) * 6;
            const float2 wa = *(const float2*)wp;
            const float2 wb = *(const float2*)(wp + 2);
            const float2 wc = *(const float2*)(wp + 4);
            const float b = b2w[i * 256 + o];
#pragma unroll
            for (int te = 0; te < TE2; te += 2) {
                float dx = b, dy = b;
                dx = fmaf(ear[te][0], wa.x, dx); dy = fmaf(ear[te+1][0], wa.x, dy);
                dx = fmaf(ear[te][1], wa.y, dx); dy = fmaf(ear[te+1][1], wa.y, dy);
                dx = fmaf(ear[te][2], wb.x, dx); dy = fmaf(ear[te+1][2], wb.x, dy);
                dx = fmaf(ear[te][3], wb.y, dx); dy = fmaf(ear[te+1][3], wb.y, dy);
                dx = fmaf(ear[te][4], wc.x, dx); dy = fmaf(ear[te+1][4], wc.x, dy);
                dx = fmaf(ear[te][5], wc.y, dx); dy = fmaf(ear[te+1][5], wc.y, dy);
                dx = fmaxf(dx, 0.f);             dy = fmaxf(dy, 0.f);
                acc[te]   = fmaf(xsS[te * 128 + il], dx, acc[te]);
                acc[te+1] = fmaf(xsS[(te+1) * 128 + il], dy, acc[te+1]);
            }
        }
        if (ich == 1) {
#pragma unroll
            for (int te = 0; te < TE2; te++) partS[te * 256 + o] = acc[te];
        }
        __syncthreads();
        if (ich == 0) {
#pragma unroll
            for (int te = 0; te < TE2; te++)
                atomicAdd(ws + OFF_AGG2 + rep * 8960 + dstsS[te] * 256 + o,
                          acc[te] + partS[te * 256 + o]);
        }
    }
    gbar(bar, NBLK * 2u);

    // ---------------- PC: x2 = relu(sum(agg2 reps)/c + lin2.x1 + b2) -------
    if (bid < 140) {
        const int n = bid >> 2, og = bid & 3;
        float* x1S = smem;               // 256
        float* partS = smem + 256;       // 8*64
        float* cS = smem + 768;          // 1
        if (tid == 0) cS[0] = ld_c(ws + OFF_CNT + n);
        if (tid >= 128 && tid < 256) {
            const int ip = (tid - 128) * 2;
            *(float2*)&x1S[ip] = ld_c2(ws + OFF_X1 + n * 256 + ip);
        }
        __syncthreads();
        const int ol = tid & 63, ic = tid >> 6;
        const int o = og * 64 + ol;
        const float4* l4 = (const float4*)(lin2 + (size_t)o * 256 + ic * 32);
        const float* xs = x1S + ic * 32;
        float s = 0.f;
#pragma unroll
        for (int k = 0; k < 8; k++) {
            const float4 wv = l4[k];
            s = fmaf(wv.x, xs[k * 4], s);
            s = fmaf(wv.y, xs[k * 4 + 1], s);
            s = fmaf(wv.z, xs[k * 4 + 2], s);
            s = fmaf(wv.w, xs[k * 4 + 3], s);
        }
        partS[ic * 64 + ol] = s;
        __syncthreads();
        if (ic == 0) {
            float t = s;
#pragma unroll
            for (int p = 1; p < 8; p++) t += partS[p * 64 + ol];
            float g = 0.f;
#pragma unroll
            for (int r = 0; r < 4; r++)
                g += ld_c(ws + OFF_AGG2 + r * 8960 + n * 256 + o);
            const float c = fmaxf(cS[0], 1.f);
            st_c(ws + OFF_X2 + n * 256 + o, fmaxf(g / c + t + b2[o], 0.f));
        }
    }
    gbar(bar, NBLK * 3u);

    // ---------------- PD: layer-3 edge messages -> agg3 replica ------------
    {
        const int e0 = bid * TE3;
        const int rep = bid & 3;
        int* srcsS = (int*)smem;         // 5
        int* dstsS = (int*)smem + 8;     // 5
        float* easS = smem + 16;         // 30
        float* xsS = smem + 64;          // 5*256 -> ends 1344
        float* partS = smem + 1344;      // 7*5*64 -> ends 3584
        if (tid < TE3) { srcsS[tid] = ei[e0 + tid]; dstsS[tid] = ei[NE + e0 + tid]; }
        if (tid >= 64 && tid < 64 + TE3 * 6) {
            const int t = tid - 64;
            easS[t] = ea[e0 * 6 + t];
        }
        __syncthreads();
        for (int idx = tid; idx < TE3 * 128; idx += 512) {
            const int te = idx >> 7, ip = (idx & 127) * 2;
            *(float2*)&xsS[te * 256 + ip] =
                ld_c2(ws + OFF_X2 + srcsS[te] * 256 + ip);
        }
        __syncthreads();
        const int o3 = tid & 63, ic = tid >> 6;
        float ear[TE3][6];
#pragma unroll
        for (int te = 0; te < TE3; te++)
#pragma unroll
            for (int v = 0; v < 6; v++) ear[te][v] = easS[te * 6 + v];
        float acc[TE3] = {};
        for (int ii = 0; ii < 32; ii++) {
            const int i = ic * 32 + ii;
            const float* wp = w3 + (size_t)(i * 64 + o3) * 6;
            const float2 wa = *(const float2*)wp;
            const float2 wb = *(const float2*)(wp + 2);
            const float2 wc = *(const float2*)(wp + 4);
            const float b = b3w[i * 64 + o3];
#pragma unroll
            for (int te = 0; te < TE3; te++) {
                float d = b;
                d = fmaf(ear[te][0], wa.x, d);
                d = fmaf(ear[te][1], wa.y, d);
                d = fmaf(ear[te][2], wb.x, d);
                d = fmaf(ear[te][3], wb.y, d);
                d = fmaf(ear[te][4], wc.x, d);
                d = fmaf(ear[te][5], wc.y, d);
                acc[te] = fmaf(xsS[te * 256 + i], fmaxf(d, 0.f), acc[te]);
            }
        }
        if (ic > 0) {
#pragma unroll
            for (int te = 0; te < TE3; te++)
                partS[(ic - 1) * 320 + te * 64 + o3] = acc[te];
        }
        __syncthreads();
        if (ic == 0) {
#pragma unroll
            for (int te = 0; te < TE3; te++) {
                float s = acc[te];
#pragma unroll
                for (int p = 0; p < 7; p++) s += partS[p * 320 + te * 64 + o3];
                atomicAdd(ws + OFF_AGG3 + rep * 2240 + dstsS[te] * 64 + o3, s);
            }
        }
    }
    gbar(bar, NBLK * 4u);

    // ---------------- PE: x3 (own node) + 35-flag + CBT --------------------
    if (bid >= NN) return;
    {
        const int n = bid;
        float* x2S = smem;               // 256
        float* partS = smem + 256;       // 8*64
        float* cS = smem + 768;          // 1
        if (tid == 0) cS[0] = ld_c(ws + OFF_CNT + n);
        if (tid >= 128 && tid < 256) {
            const int ip = (tid - 128) * 2;
            *(float2*)&x2S[ip] = ld_c2(ws + OFF_X2 + n * 256 + ip);
        }
        __syncthreads();
        const int o3 = tid & 63, ic = tid >> 6;
        const float4* l4 = (const float4*)(lin3 + (size_t)o3 * 256 + ic * 32);
        const float* xs = x2S + ic * 32;
        float s = 0.f;
#pragma unroll
        for (int k = 0; k < 8; k++) {
            const float4 wv = l4[k];
            s = fmaf(wv.x, xs[k * 4], s);
            s = fmaf(wv.y, xs[k * 4 + 1], s);
            s = fmaf(wv.z, xs[k * 4 + 2], s);
            s = fmaf(wv.w, xs[k * 4 + 3], s);
        }
        partS[ic * 64 + o3] = s;
        __syncthreads();
        if (ic == 0) {
            float t = s;
#pragma unroll
            for (int p = 1; p < 8; p++) t += partS[p * 64 + o3];
            float g = 0.f;
#pragma unroll
            for (int r = 0; r < 4; r++)
                g += ld_c(ws + OFF_AGG3 + r * 2240 + n * 64 + o3);
            const float c = fmaxf(cS[0], 1.f);
            st_c(ws + OFF_X3 + n * 64 + o3, fmaxf(g / c + t + b3[o3], 0.f));
        }
        // 35-way flag: x3 stores drained by __syncthreads (vmcnt), then arrive
        __syncthreads();
        if (tid == 0) {
            unsigned* flag = bar + 128;
            __hip_atomic_fetch_add(flag, 1u, __ATOMIC_RELAXED,
                                   __HIP_MEMORY_SCOPE_AGENT);
            while (__hip_atomic_load(flag, __ATOMIC_RELAXED,
                                     __HIP_MEMORY_SCOPE_AGENT) < NN)
                __builtin_amdgcn_s_sleep(4);
            asm volatile("" ::: "memory");
        }
        __syncthreads();
        // CBT
        float* sx = smem;  // 2240
        for (int idx = tid; idx < NN * 32; idx += 512)
            *(float2*)&sx[idx * 2] = ld_c2(ws + OFF_X3 + idx * 2);
        __syncthreads();
        const int f = tid & 63, jg = tid >> 6;
        const float xi = sx[bid * 64 + f];
        for (int j = jg; j < NN; j += 8) {
            float d = fabsf(xi - sx[j * 64 + f]);
#pragma unroll
            for (int off = 32; off > 0; off >>= 1) d += __shfl_xor(d, off);
            if (f == 0) out[bid * NN + j] = d;
        }
    }
}

extern "C" void kernel_launch(void* const* d_in, const int* in_sizes, int n_in,
                              void* d_out, int out_size, void* d_ws, size_t ws_size,
                              hipStream_t stream) {
    (void)in_sizes; (void)n_in; (void)out_size; (void)ws_size;
    const float* x    = (const float*)d_in[0];
    const float* ea   = (const float*)d_in[1];
    const int*   ei   = (const int*)d_in[2];
    const float* nn1w = (const float*)d_in[3];
    const float* nn1b = (const float*)d_in[4];
    const float* lin1 = (const float*)d_in[5];
    const float* b1   = (const float*)d_in[6];
    const float* nn2w = (const float*)d_in[7];
    const float* nn2b = (const float*)d_in[8];
    const float* lin2 = (const float*)d_in[9];
    const float* b2   = (const float*)d_in[10];
    const float* nn3w = (const float*)d_in[11];
    const float* nn3b = (const float*)d_in[12];
    const float* lin3 = (const float*)d_in[13];
    const float* b3   = (const float*)d_in[14];

    float* ws = (float*)d_ws;
    init_k<<<1, 64, 0, stream>>>((unsigned*)d_ws);
    mega_k<<<NBLK, 512, 0, stream>>>(ws, x, ea, ei, nn1w, nn1b, lin1, b1,
                                     nn2w, nn2b, lin2, b2, nn3w, nn3b,
                                     lin3, b3, (float*)d_out);
}